// Round 17
// baseline (91.905 us; speedup 1.0000x reference)
//
#include <hip/hip_runtime.h>
#include <hip/hip_bf16.h>

// Conv2d 3x3 s1 p1, NCHW: X(32,128,56,56) f32 * W(256,128,3,3) f32 -> out(32,256,56,56) f32
// R17 = R10 (68.2us best) + half-tap B-prefetch (intra-wave read/MFMA overlap):
// tap split into half0 (j=0..3) / half1 (j=4..6). bPf[2][4]: slot = half parity
// (tap*2+h parity == h, all indices static). During half-h's 12-16 MFMAs the wave
// issues next half's ds_reads into the other slot => ~250-300cy cover per read
// (R8 failed: 4-inst distance; R9 failed: full-tap prefetch spilled 112 regs).
// Slice prologue re-reads half(0,0) after the barrier. A-prefetch/staging/sync
// byte-identical to R10. Prepass = R16's fused pad+border (passed).

#define IC 128
#define OC 256
#define HH 56
#define WW 56
#define NB 32
#define PH 58
#define PW 58
#define PS (PH*PW)
#define NPIX (HH*WW)      // 3136
#define GPIX (NB*NPIX)    // 100352
#define KDIM (IC*9)       // 1152

#define BMH 128           // oc per block
#define BNP 448           // pixels per block (8 rows x 56)

#define WROWB 3712        // window row stride bytes: 58 cols x 64B
#define WINREAL 37120     // 10 rows x 3712
#define WINB 37888        // buffer size incl. staging slack

#define PADBLK 1568       // interior pad blocks (GPIX/64)
#define BORDBLK 456       // border blocks: 32*228*16 slots / 256

typedef short  bf16x8 __attribute__((ext_vector_type(8)));
typedef float  f32x4  __attribute__((ext_vector_type(4)));
typedef unsigned int u32;

__device__ __forceinline__ unsigned short f2bf(float f) {
  union { float f; unsigned int u; } c; c.f = f;
  unsigned int u = c.u;
  u += 0x7FFFu + ((u >> 16) & 1u);
  return (unsigned short)(u >> 16);
}

__device__ __forceinline__ void gload16(const unsigned short* g, unsigned short* l) {
  __builtin_amdgcn_global_load_lds(
      (const __attribute__((address_space(1))) u32*)g,
      (__attribute__((address_space(3))) u32*)l, 16, 0, 0);
}

// involution on bytes: bits 4-7 ^= bits 8-11
__device__ __forceinline__ int swz(int a) { return a ^ (((a >> 8) & 15) << 4); }

// ---- prepass 1 (fused): NCHW f32 -> NHWC-padded bf16 transpose + border zeroing
__global__ __launch_bounds__(256) void pad_x_nhwc(const float* __restrict__ X,
                                                  unsigned short* __restrict__ Xt) {
  if (blockIdx.x >= PADBLK) {
    int slot = (blockIdx.x - PADBLK) * 256 + threadIdx.x;
    if (slot >= NB * 228 * 16) return;
    int n  = slot / 3648;
    int r  = slot - n * 3648;
    int bp = r >> 4;
    int e8 = r & 15;
    int y, x;
    if (bp < 58)       { y = 0;  x = bp; }
    else if (bp < 116) { y = 57; x = bp - 58; }
    else {
      int b2 = bp - 116;
      y = 1 + (b2 >> 1);
      x = (b2 & 1) * 57;
    }
    bf16x8 z = (bf16x8)(short)0;
    *reinterpret_cast<bf16x8*>(
        Xt + ((long)(n * PH + y) * PW + x) * IC + e8 * 8) = z;
    return;
  }

  __shared__ float tile[128][65];
  const int t   = threadIdx.x;
  const int p0  = blockIdx.x * 64;
  const int n   = p0 / NPIX;
  const int rem = p0 - n * NPIX;

  const int pixl = t & 63;
  const int q    = t >> 6;
  const float* src = X + ((long)n * IC + q) * NPIX + rem + pixl;
  #pragma unroll
  for (int i = 0; i < 32; ++i)
    tile[q + i * 4][pixl] = src[(long)i * 4 * NPIX];
  __syncthreads();

  const int pix = t >> 2;
  const int icq = (t & 3) * 32;
  int p = rem + pix;
  int y = p / WW, x = p - y * WW;
  unsigned short* dst = Xt + ((long)(n * PH + y + 1) * PW + (x + 1)) * IC + icq;
  #pragma unroll
  for (int g = 0; g < 4; ++g) {
    bf16x8 v;
    #pragma unroll
    for (int j = 0; j < 8; ++j)
      ((unsigned short*)&v)[j] = f2bf(tile[icq + g * 8 + j][pix]);
    *reinterpret_cast<bf16x8*>(dst + g * 8) = v;
  }
}

// ---- prepass 2: W (OIHW f32) -> Wb bf16 [tap][ic_octet s][oc][8 ic]
__global__ __launch_bounds__(256) void pack_w(const float* __restrict__ W,
                                              unsigned short* __restrict__ Wb, int total) {
  int idx = blockIdx.x * 256 + threadIdx.x;
  if (idx >= total) return;
  int e  = idx & 7;
  int oc = (idx >> 3) & 255;
  int s  = (idx >> 11) & 15;
  int t  = idx >> 15;
  Wb[idx] = f2bf(W[(oc * IC + s * 8 + e) * 9 + t]);
}

// ---- main: halo-window implicit GEMM, half-tap B-pipeline
__global__ __launch_bounds__(512) void conv_win(
    const unsigned short* __restrict__ Xt,
    const unsigned short* __restrict__ Wb,
    float* __restrict__ out) {
  __shared__ __align__(16) unsigned short lds[37888];   // 75776 B: 2 window buffers
  char* const ldsb = (char*)lds;

  const int tid  = threadIdx.x;
  const int lane = tid & 63;
  const int w    = tid >> 6;
  const int wm = w >> 2, wn = w & 3;     // 2M x 4N wave grid; wave tile 64oc x 112px
  const int l15 = lane & 15, lh = lane >> 4;

  // XCD-aware bijective remap: 448 = 8 x 56
  const int bid   = blockIdx.x;
  const int wg    = (bid & 7) * 56 + (bid >> 3);
  const int ntile = wg >> 1;             // 0..223
  const int mhalf = wg & 1;
  const int n   = ntile / 7;
  const int rg  = ntile - n * 7;
  const int y0  = rg * 8;                // padded top row of window
  const int ocb = mhalf * BMH;

  // ---- A source: per-lane VGPR loads, coalesced (16 lanes x 16B contiguous)
  const unsigned short* aBase = Wb + (size_t)lh * 2048 + (ocb + wm * 64 + l15) * 8;

  // ---- window staging sources (5 slots/thread; content layout [10][58 cols][64B])
  const unsigned short* srcW[5];
  #pragma unroll
  for (int r = 0; r < 5; ++r) {
    int xw = swz((tid + r * 512) * 16);
    if (xw >= WINREAL) xw = WINREAL - 16;          // slack slots: dup last (never read)
    int row = xw / WROWB;
    int rem = xw - row * WROWB;
    int col = rem >> 6;
    srcW[r] = Xt + ((long)((n * PH + y0 + row) * PW + col)) * IC + ((rem & 63) >> 1);
  }

  // ---- fragment linear offsets (window, stride-58 rows)
  int pixLin[7];
  #pragma unroll
  for (int j = 0; j < 7; ++j) {
    int local = wn * 112 + j * 16 + l15;     // 0..447 within block
    int wy = local / 56, wx = local - wy * 56;
    pixLin[j] = (wy * 58 + wx) * 64 + lh * 16;
  }

  f32x4 acc[4][7];
  #pragma unroll
  for (int m = 0; m < 4; ++m)
    #pragma unroll
    for (int j = 0; j < 7; ++j)
      acc[m][j] = (f32x4){0.f, 0.f, 0.f, 0.f};

  auto stageWin = [&](int icb) {          // slice icb -> buf (icb&1); wave-uniform dest
    char* base = ldsb + (icb & 1) * WINB + (tid & ~63) * 16;
    #pragma unroll
    for (int r = 0; r < 5; ++r)
      if (r < 4 || w <= 4)                // call 4: waves 5-7 skip (slots beyond slack)
        gload16(srcW[r] + icb * 32, (unsigned short*)(base + r * 8192));
  };

  // ---- prologue
  stageWin(0);
  bf16x8 aReg[2][4];
  #pragma unroll
  for (int m = 0; m < 4; ++m)
    aReg[0][m] = *(const bf16x8*)(aBase + m * 128);        // A(q=0): tap0, icb0
  asm volatile("s_waitcnt vmcnt(0)" ::: "memory");
  __builtin_amdgcn_s_barrier();
  __builtin_amdgcn_sched_barrier(0);

  bf16x8 bPf[2][4];    // [half parity][frag]; h=0 -> j 0..3, h=1 -> j 4..6

  for (int icb = 0; icb < 4; ++icb) {
    const int winSel = (icb & 1) * WINB;

    // slice prologue: half (tap0, h0) -> bPf[0]  (window certified at barrier)
    #pragma unroll
    for (int j = 0; j < 4; ++j)
      bPf[0][j] = *(const bf16x8*)(ldsb + winSel + swz(pixLin[j]));

    #pragma unroll
    for (int tap = 0; tap < 9; ++tap) {
      // global tap parity: q = icb*9+tap ; 9 odd => q&1 == (icb+tap)&1
      const int rs = (icb + tap) & 1;          // A read slot
      const int ps = rs ^ 1;                   // A prefetch slot (q+1)

      const int dy = tap / 3, dx = tap - dy * 3;       // compile-time
      const int toff = (dy * 58 + dx) * 64;

      // ===== half 0 =====
      // B-prefetch: this tap's half1 -> bPf[1] (consumed after 16 MFMAs)
      #pragma unroll
      for (int j = 0; j < 3; ++j)
        bPf[1][j] = *(const bf16x8*)(ldsb + winSel + swz(pixLin[4 + j] + toff));

      // A-prefetch for q+1 (never collides: ps != rs)
      if (tap < 8) {
        #pragma unroll
        for (int m = 0; m < 4; ++m)
          aReg[ps][m] = *(const bf16x8*)(aBase + (size_t)(tap + 1) * 32768
                                               + (size_t)icb * 8192 + m * 128);
      } else if (icb < 3) {
        #pragma unroll
        for (int m = 0; m < 4; ++m)
          aReg[ps][m] = *(const bf16x8*)(aBase + (size_t)(icb + 1) * 8192 + m * 128);
      }

      __builtin_amdgcn_s_setprio(1);
      #pragma unroll
      for (int j = 0; j < 4; ++j)
        #pragma unroll
        for (int m = 0; m < 4; ++m)
          acc[m][j] = __builtin_amdgcn_mfma_f32_16x16x32_bf16(aReg[rs][m], bPf[0][j],
                                                              acc[m][j], 0, 0, 0);
      __builtin_amdgcn_s_setprio(0);

      // ===== half 1 =====
      // B-prefetch: next tap's half0 -> bPf[0] (skip at slice end; re-read after barrier)
      if (tap < 8) {
        const int nt = tap + 1;
        const int ndy = nt / 3, ndx = nt - ndy * 3;
        const int ntoff = (ndy * 58 + ndx) * 64;
        #pragma unroll
        for (int j = 0; j < 4; ++j)
          bPf[0][j] = *(const bf16x8*)(ldsb + winSel + swz(pixLin[j] + ntoff));
      }

      __builtin_amdgcn_s_setprio(1);
      #pragma unroll
      for (int j = 0; j < 3; ++j)
        #pragma unroll
        for (int m = 0; m < 4; ++m)
          acc[m][4 + j] = __builtin_amdgcn_mfma_f32_16x16x32_bf16(aReg[rs][m], bPf[1][j],
                                                                  acc[m][4 + j], 0, 0, 0);
      __builtin_amdgcn_s_setprio(0);

      // FIFO-aware staging: after tap 4 (A-prefetch waits at taps<=5 don't retire it)
      if (tap == 4 && icb < 3) stageWin(icb + 1);
    }

    // window(icb+1) fully staged (all waves) before reading it; WAR on buf icb&1
    // certified for the stage at icb+2 by this same barrier.
    asm volatile("s_waitcnt vmcnt(0)" ::: "memory");
    __builtin_amdgcn_s_barrier();
    __builtin_amdgcn_sched_barrier(0);
  }

  // ---- epilogue: D row=(lane>>4)*4+reg (oc), col=lane&15 (pixel)
  #pragma unroll
  for (int j = 0; j < 7; ++j) {
    int local = wn * 112 + j * 16 + l15;
    int pidx  = rg * BNP + local;                 // pixel within image
    #pragma unroll
    for (int m = 0; m < 4; ++m) {
      int oc = ocb + wm * 64 + m * 16 + lh * 4;
      float* op = out + ((long)(n * OC + oc)) * NPIX + pidx;
      #pragma unroll
      for (int r = 0; r < 4; ++r)
        op[(long)r * NPIX] = acc[m][j][r];
    }
  }
}

// ---- fallback: naive direct conv fp32
__global__ __launch_bounds__(256) void conv_naive(const float* __restrict__ X,
                                                  const float* __restrict__ W,
                                                  float* __restrict__ out, int total) {
  int idx = blockIdx.x * 256 + threadIdx.x;
  if (idx >= total) return;
  int prow = idx % NPIX;
  int t    = idx / NPIX;
  int oc   = t % OC;
  int n    = t / OC;
  int oh = prow / WW, ow = prow % WW;
  float s = 0.f;
  for (int ic = 0; ic < IC; ++ic) {
    const float* xp = X + ((long)(n * IC + ic)) * NPIX;
    const float* wp = W + ((long)(oc * IC + ic)) * 9;
    #pragma unroll
    for (int kh = 0; kh < 3; ++kh) {
      int ih = oh + kh - 1;
      if (ih < 0 || ih >= HH) continue;
      #pragma unroll
      for (int kw = 0; kw < 3; ++kw) {
        int iw = ow + kw - 1;
        if (iw < 0 || iw >= WW) continue;
        s += xp[ih * WW + iw] * wp[kh * 3 + kw];
      }
    }
  }
  out[idx] = s;
}

extern "C" void kernel_launch(void* const* d_in, const int* in_sizes, int n_in,
                              void* d_out, int out_size, void* d_ws, size_t ws_size,
                              hipStream_t stream) {
  const float* X = (const float*)d_in[0];
  const float* W = (const float*)d_in[1];
  float* out = (float*)d_out;

  const size_t xt_elems = (size_t)NB * PS * IC;
  const size_t wb_elems = (size_t)9 * 16 * 256 * 8;   // 294,912
  const size_t need = (xt_elems + wb_elems) * sizeof(unsigned short);

  if (ws_size >= need) {
    unsigned short* Xt = (unsigned short*)d_ws;
    unsigned short* Wb = Xt + xt_elems;

    pad_x_nhwc<<<PADBLK + BORDBLK, 256, 0, stream>>>(X, Xt);
    int totW = (int)wb_elems;
    pack_w<<<(totW + 255) / 256, 256, 0, stream>>>(W, Wb, totW);
    conv_win<<<(GPIX / BNP) * (OC / BMH), 512, 0, stream>>>(Xt, Wb, out);
  } else {
    int tot = NB * OC * NPIX;
    conv_naive<<<(tot + 255) / 256, 256, 0, stream>>>(X, W, out, tot);
  }
}

// Round 18
// 77.850 us; speedup vs baseline: 1.1806x; 1.1806x over previous
//
#include <hip/hip_runtime.h>
#include <hip/hip_bf16.h>

// Conv2d 3x3 s1 p1, NCHW: X(32,128,56,56) f32 * W(256,128,3,3) f32 -> out(32,256,56,56) f32
// R18 = R16 + __launch_bounds__(128, 2) on conv_win. R16 post-mortem: compiler used
// 160 arch VGPRs -> 160+112 AGPR = 272 > 256 -> 1 wave/SIMD (occ 9%!) - the intended
// "4 independent blocks/CU" never happened. The (128,2) bound caps unified regs at
// 256/wave (arch <=144; body needs ~128) -> 2 waves/SIMD -> 4 blocks/CU resident with
// INDEPENDENT barriers (natural de-phasing) + 100% packing (grid 1792 = 7*256).
// Body otherwise byte-identical to R16/R10: halo-window dbuf, aReg global-tap-parity
// prefetch from L2, swz'd reads, staging after tap 4, one vmcnt(0)+barrier per slice.

#define IC 128
#define OC 256
#define HH 56
#define WW 56
#define NB 32
#define PH 58
#define PW 58
#define PS (PH*PW)
#define NPIX (HH*WW)      // 3136
#define GPIX (NB*NPIX)    // 100352
#define KDIM (IC*9)       // 1152

#define BNP 112           // pixels per block (2 rows of 56)
#define WROWB 3712        // window row stride bytes: 58 cols x 64B
#define WINREAL 14848     // 4 rows x 3712
#define WINB 16384        // buffer stride (1024 slots of 16B; 96 slack)

#define PADBLK 1568       // interior pad blocks (GPIX/64)
#define BORDBLK 456       // border blocks: 32*228*16 slots / 256

typedef short  bf16x8 __attribute__((ext_vector_type(8)));
typedef float  f32x4  __attribute__((ext_vector_type(4)));
typedef unsigned int u32;

__device__ __forceinline__ unsigned short f2bf(float f) {
  union { float f; unsigned int u; } c; c.f = f;
  unsigned int u = c.u;
  u += 0x7FFFu + ((u >> 16) & 1u);
  return (unsigned short)(u >> 16);
}

__device__ __forceinline__ void gload16(const unsigned short* g, unsigned short* l) {
  __builtin_amdgcn_global_load_lds(
      (const __attribute__((address_space(1))) u32*)g,
      (__attribute__((address_space(3))) u32*)l, 16, 0, 0);
}

// involution on bytes: bits 4-7 ^= bits 8-11 (applied to content offsets only)
__device__ __forceinline__ int swz(int a) { return a ^ (((a >> 8) & 15) << 4); }

// ---- prepass 1 (fused): NCHW f32 -> NHWC-padded bf16 transpose + border zeroing
__global__ __launch_bounds__(256) void pad_x_nhwc(const float* __restrict__ X,
                                                  unsigned short* __restrict__ Xt) {
  if (blockIdx.x >= PADBLK) {
    int slot = (blockIdx.x - PADBLK) * 256 + threadIdx.x;
    if (slot >= NB * 228 * 16) return;
    int n  = slot / 3648;
    int r  = slot - n * 3648;
    int bp = r >> 4;
    int e8 = r & 15;
    int y, x;
    if (bp < 58)       { y = 0;  x = bp; }
    else if (bp < 116) { y = 57; x = bp - 58; }
    else {
      int b2 = bp - 116;
      y = 1 + (b2 >> 1);
      x = (b2 & 1) * 57;
    }
    bf16x8 z = (bf16x8)(short)0;
    *reinterpret_cast<bf16x8*>(
        Xt + ((long)(n * PH + y) * PW + x) * IC + e8 * 8) = z;
    return;
  }

  __shared__ float tile[128][65];
  const int t   = threadIdx.x;
  const int p0  = blockIdx.x * 64;
  const int n   = p0 / NPIX;
  const int rem = p0 - n * NPIX;

  const int pixl = t & 63;
  const int q    = t >> 6;
  const float* src = X + ((long)n * IC + q) * NPIX + rem + pixl;
  #pragma unroll
  for (int i = 0; i < 32; ++i)
    tile[q + i * 4][pixl] = src[(long)i * 4 * NPIX];
  __syncthreads();

  const int pix = t >> 2;
  const int icq = (t & 3) * 32;
  int p = rem + pix;
  int y = p / WW, x = p - y * WW;
  unsigned short* dst = Xt + ((long)(n * PH + y + 1) * PW + (x + 1)) * IC + icq;
  #pragma unroll
  for (int g = 0; g < 4; ++g) {
    bf16x8 v;
    #pragma unroll
    for (int j = 0; j < 8; ++j)
      ((unsigned short*)&v)[j] = f2bf(tile[icq + g * 8 + j][pix]);
    *reinterpret_cast<bf16x8*>(dst + g * 8) = v;
  }
}

// ---- prepass 2: W (OIHW f32) -> Wb bf16 [tap][ic_octet s][oc][8 ic]
__global__ __launch_bounds__(256) void pack_w(const float* __restrict__ W,
                                              unsigned short* __restrict__ Wb, int total) {
  int idx = blockIdx.x * 256 + threadIdx.x;
  if (idx >= total) return;
  int e  = idx & 7;
  int oc = (idx >> 3) & 255;
  int s  = (idx >> 11) & 15;
  int t  = idx >> 15;
  Wb[idx] = f2bf(W[(oc * IC + s * 8 + e) * 9 + t]);
}

// ---- main: halo-window implicit GEMM, 128oc x 112px blocks, 2 waves, reg-capped
__global__ __launch_bounds__(128, 2) void conv_win(
    const unsigned short* __restrict__ Xt,
    const unsigned short* __restrict__ Wb,
    float* __restrict__ out) {
  __shared__ __align__(16) unsigned short lds[16384];   // 32 KB: 2 window buffers
  char* const ldsb = (char*)lds;

  const int tid  = threadIdx.x;
  const int lane = tid & 63;
  const int wm   = tid >> 6;             // 2 waves: M halves; wave tile 64oc x 112px
  const int l15 = lane & 15, lh = lane >> 4;

  // XCD-aware bijective remap: 1792 = 8 x 224; wg pairs share a pixel tile
  const int bid = blockIdx.x;
  const int wg  = (bid & 7) * 224 + (bid >> 3);
  const int pt  = wg >> 1;               // pixel-tile 0..895
  const int ocb = (wg & 1) * 128;
  const int n   = pt / 28;
  const int rt  = pt - n * 28;           // row-pair within image
  const int y0  = rt * 2;                // padded top row of window (4 rows)

  // ---- A source: per-lane VGPR loads, coalesced (16 lanes x 16B contiguous)
  const unsigned short* aBase = Wb + (size_t)lh * 2048 + (ocb + wm * 64 + l15) * 8;

  // ---- window staging sources (8 slots/thread; content layout [4][58 cols][64B])
  const unsigned short* srcW[8];
  #pragma unroll
  for (int r = 0; r < 8; ++r) {
    int xw = swz((r * 128 + tid) * 16);
    if (xw >= WINREAL) xw = WINREAL - 16;          // slack slots: dup (never read)
    int row = xw / WROWB;
    int rem = xw - row * WROWB;
    int col = rem >> 6;
    srcW[r] = Xt + ((long)((n * PH + y0 + row) * PW + col)) * IC + ((rem & 63) >> 1);
  }

  // ---- fragment linear offsets (window, stride-58 rows)
  int pixLin[7];
  #pragma unroll
  for (int j = 0; j < 7; ++j) {
    int local = j * 16 + l15;                // 0..111 within block
    int wy = local / 56, wx = local - wy * 56;
    pixLin[j] = (wy * 58 + wx) * 64 + lh * 16;
  }

  f32x4 acc[4][7];
  #pragma unroll
  for (int m = 0; m < 4; ++m)
    #pragma unroll
    for (int j = 0; j < 7; ++j)
      acc[m][j] = (f32x4){0.f, 0.f, 0.f, 0.f};

  auto stageWin = [&](int icb) {          // slice icb -> buf (icb&1); wave-uniform dest
    char* base = ldsb + (icb & 1) * WINB + (tid & ~63) * 16;
    #pragma unroll
    for (int r = 0; r < 8; ++r)
      gload16(srcW[r] + icb * 32, (unsigned short*)(base + r * 2048));
  };

  // ---- prologue
  stageWin(0);
  bf16x8 aReg[2][4];
  #pragma unroll
  for (int m = 0; m < 4; ++m)
    aReg[0][m] = *(const bf16x8*)(aBase + m * 128);        // A(q=0): tap0, icb0
  asm volatile("s_waitcnt vmcnt(0)" ::: "memory");
  __builtin_amdgcn_s_barrier();
  __builtin_amdgcn_sched_barrier(0);

  for (int icb = 0; icb < 4; ++icb) {
    const int winSel = (icb & 1) * WINB;

    #pragma unroll
    for (int tap = 0; tap < 9; ++tap) {
      // global tap parity: q = icb*9+tap ; 9 odd => q&1 == (icb+tap)&1
      const int rs = (icb + tap) & 1;          // read slot
      const int ps = rs ^ 1;                   // prefetch slot (q+1)

      // prefetch A for q+1 (never collides: ps != rs)
      if (tap < 8) {
        #pragma unroll
        for (int m = 0; m < 4; ++m)
          aReg[ps][m] = *(const bf16x8*)(aBase + (size_t)(tap + 1) * 32768
                                               + (size_t)icb * 8192 + m * 128);
      } else if (icb < 3) {
        #pragma unroll
        for (int m = 0; m < 4; ++m)
          aReg[ps][m] = *(const bf16x8*)(aBase + (size_t)(icb + 1) * 8192 + m * 128);
      }

      const int dy = tap / 3, dx = tap - dy * 3;   // compile-time (tap unrolled)
      const int toff = (dy * 58 + dx) * 64;

      bf16x8 bfv[7];
      #pragma unroll
      for (int j = 0; j < 7; ++j)
        bfv[j] = *(const bf16x8*)(ldsb + winSel + swz(pixLin[j] + toff));

      __builtin_amdgcn_s_setprio(1);
      #pragma unroll
      for (int j = 0; j < 7; ++j)
        #pragma unroll
        for (int m = 0; m < 4; ++m)
          acc[m][j] = __builtin_amdgcn_mfma_f32_16x16x32_bf16(aReg[rs][m], bfv[j],
                                                              acc[m][j], 0, 0, 0);
      __builtin_amdgcn_s_setprio(0);

      // FIFO-aware staging: issue after tap 4 so A-prefetch waits at taps<=5 do not
      // force-retire the staging burst (vmcnt retires oldest-first).
      if (tap == 4 && icb < 3) stageWin(icb + 1);
    }

    // window(icb+1) fully staged (both waves) before reading it; WAR on buf icb&1
    // certified for the stage at icb+2 by this same barrier.
    asm volatile("s_waitcnt vmcnt(0)" ::: "memory");
    __builtin_amdgcn_s_barrier();
    __builtin_amdgcn_sched_barrier(0);
  }

  // ---- epilogue: D row=(lane>>4)*4+reg (oc), col=lane&15 (pixel)
  #pragma unroll
  for (int j = 0; j < 7; ++j) {
    int pidx = rt * BNP + j * 16 + l15;           // pixel within image
    #pragma unroll
    for (int m = 0; m < 4; ++m) {
      int oc = ocb + wm * 64 + m * 16 + lh * 4;
      float* op = out + ((long)(n * OC + oc)) * NPIX + pidx;
      #pragma unroll
      for (int r = 0; r < 4; ++r)
        op[(long)r * NPIX] = acc[m][j][r];
    }
  }
}

// ---- fallback: naive direct conv fp32
__global__ __launch_bounds__(256) void conv_naive(const float* __restrict__ X,
                                                  const float* __restrict__ W,
                                                  float* __restrict__ out, int total) {
  int idx = blockIdx.x * 256 + threadIdx.x;
  if (idx >= total) return;
  int prow = idx % NPIX;
  int t    = idx / NPIX;
  int oc   = t % OC;
  int n    = t / OC;
  int oh = prow / WW, ow = prow % WW;
  float s = 0.f;
  for (int ic = 0; ic < IC; ++ic) {
    const float* xp = X + ((long)(n * IC + ic)) * NPIX;
    const float* wp = W + ((long)(oc * IC + ic)) * 9;
    #pragma unroll
    for (int kh = 0; kh < 3; ++kh) {
      int ih = oh + kh - 1;
      if (ih < 0 || ih >= HH) continue;
      #pragma unroll
      for (int kw = 0; kw < 3; ++kw) {
        int iw = ow + kw - 1;
        if (iw < 0 || iw >= WW) continue;
        s += xp[ih * WW + iw] * wp[kh * 3 + kw];
      }
    }
  }
  out[idx] = s;
}

extern "C" void kernel_launch(void* const* d_in, const int* in_sizes, int n_in,
                              void* d_out, int out_size, void* d_ws, size_t ws_size,
                              hipStream_t stream) {
  const float* X = (const float*)d_in[0];
  const float* W = (const float*)d_in[1];
  float* out = (float*)d_out;

  const size_t xt_elems = (size_t)NB * PS * IC;
  const size_t wb_elems = (size_t)9 * 16 * 256 * 8;   // 294,912
  const size_t need = (xt_elems + wb_elems) * sizeof(unsigned short);

  if (ws_size >= need) {
    unsigned short* Xt = (unsigned short*)d_ws;
    unsigned short* Wb = Xt + xt_elems;

    pad_x_nhwc<<<PADBLK + BORDBLK, 256, 0, stream>>>(X, Xt);
    int totW = (int)wb_elems;
    pack_w<<<(totW + 255) / 256, 256, 0, stream>>>(W, Wb, totW);
    conv_win<<<(GPIX / BNP) * (OC / 128), 128, 0, stream>>>(Xt, Wb, out);
  } else {
    int tot = NB * OC * NPIX;
    conv_naive<<<(tot + 255) / 256, 256, 0, stream>>>(X, W, out, tot);
  }
}

// Round 19
// 76.106 us; speedup vs baseline: 1.2076x; 1.0229x over previous
//
#include <hip/hip_runtime.h>
#include <hip/hip_bf16.h>

// Conv2d 3x3 s1 p1, NCHW: X(32,128,56,56) f32 * W(256,128,3,3) f32 -> out(32,256,56,56) f32
// R19 = R18 (62.0us main, best) + pack_w FUSED into the pad prepass (one dispatch fewer).
// Main kernel conv_win is byte-identical to R18:
//   128oc x 112px blocks, 2 waves, __launch_bounds__(128,2) => VGPR 128 + 112 AGPR = 240
//   unified => 2 waves/SIMD, multiple independent blocks/CU (de-phased barriers),
//   grid 1792 = 7*256 (100% packing), halo-window dbuf in LDS (32KB), weights L2->VGPR
//   with global-tap-parity dbuf, swz'd window reads, staging after tap 4,
//   one vmcnt(0)+s_barrier+sched_barrier per ic-slice.

#define IC 128
#define OC 256
#define HH 56
#define WW 56
#define NB 32
#define PH 58
#define PW 58
#define PS (PH*PW)
#define NPIX (HH*WW)      // 3136
#define GPIX (NB*NPIX)    // 100352
#define KDIM (IC*9)       // 1152

#define BNP 112           // pixels per block (2 rows of 56)
#define WROWB 3712        // window row stride bytes: 58 cols x 64B
#define WINREAL 14848     // 4 rows x 3712
#define WINB 16384        // buffer stride (1024 slots of 16B; 96 slack)

#define PADBLK 1568       // interior pad blocks (GPIX/64)
#define BORDBLK 456       // border blocks: 32*228*16 slots / 256
#define WBLK 144          // pack_w blocks: 294912 elems / (256 thr * 8)

typedef short  bf16x8 __attribute__((ext_vector_type(8)));
typedef float  f32x4  __attribute__((ext_vector_type(4)));
typedef unsigned int u32;

__device__ __forceinline__ unsigned short f2bf(float f) {
  union { float f; unsigned int u; } c; c.f = f;
  unsigned int u = c.u;
  u += 0x7FFFu + ((u >> 16) & 1u);
  return (unsigned short)(u >> 16);
}

__device__ __forceinline__ void gload16(const unsigned short* g, unsigned short* l) {
  __builtin_amdgcn_global_load_lds(
      (const __attribute__((address_space(1))) u32*)g,
      (__attribute__((address_space(3))) u32*)l, 16, 0, 0);
}

// involution on bytes: bits 4-7 ^= bits 8-11 (applied to content offsets only)
__device__ __forceinline__ int swz(int a) { return a ^ (((a >> 8) & 15) << 4); }

// ---- prepass (fused): X transpose+pad+convert AND W pack AND border zeroing
__global__ __launch_bounds__(256) void prep(const float* __restrict__ X,
                                            const float* __restrict__ W,
                                            unsigned short* __restrict__ Xt,
                                            unsigned short* __restrict__ Wb) {
  if (blockIdx.x >= PADBLK + BORDBLK) {
    // ---- pack_w: Wb bf16 [tap][ic_octet s][oc][8 ic], 8 elems/thread
    int base = ((int)blockIdx.x - (PADBLK + BORDBLK)) * 2048 + threadIdx.x * 8;
    int oc = (base >> 3) & 255;
    int s  = (base >> 11) & 15;
    int t  = base >> 15;
    bf16x8 v;
    #pragma unroll
    for (int e = 0; e < 8; ++e)
      ((unsigned short*)&v)[e] = f2bf(W[(oc * IC + s * 8 + e) * 9 + t]);
    *reinterpret_cast<bf16x8*>(Wb + base) = v;
    return;
  }
  if (blockIdx.x >= PADBLK) {
    // ---- border zeroing
    int slot = (blockIdx.x - PADBLK) * 256 + threadIdx.x;
    if (slot >= NB * 228 * 16) return;
    int n  = slot / 3648;
    int r  = slot - n * 3648;
    int bp = r >> 4;
    int e8 = r & 15;
    int y, x;
    if (bp < 58)       { y = 0;  x = bp; }
    else if (bp < 116) { y = 57; x = bp - 58; }
    else {
      int b2 = bp - 116;
      y = 1 + (b2 >> 1);
      x = (b2 & 1) * 57;
    }
    bf16x8 z = (bf16x8)(short)0;
    *reinterpret_cast<bf16x8*>(
        Xt + ((long)(n * PH + y) * PW + x) * IC + e8 * 8) = z;
    return;
  }

  // ---- NCHW f32 -> NHWC-padded bf16 (LDS-tiled transpose)
  __shared__ float tile[128][65];
  const int t   = threadIdx.x;
  const int p0  = blockIdx.x * 64;
  const int n   = p0 / NPIX;
  const int rem = p0 - n * NPIX;

  const int pixl = t & 63;
  const int q    = t >> 6;
  const float* src = X + ((long)n * IC + q) * NPIX + rem + pixl;
  #pragma unroll
  for (int i = 0; i < 32; ++i)
    tile[q + i * 4][pixl] = src[(long)i * 4 * NPIX];
  __syncthreads();

  const int pix = t >> 2;
  const int icq = (t & 3) * 32;
  int p = rem + pix;
  int y = p / WW, x = p - y * WW;
  unsigned short* dst = Xt + ((long)(n * PH + y + 1) * PW + (x + 1)) * IC + icq;
  #pragma unroll
  for (int g = 0; g < 4; ++g) {
    bf16x8 v;
    #pragma unroll
    for (int j = 0; j < 8; ++j)
      ((unsigned short*)&v)[j] = f2bf(tile[icq + g * 8 + j][pix]);
    *reinterpret_cast<bf16x8*>(dst + g * 8) = v;
  }
}

// ---- main: halo-window implicit GEMM, 128oc x 112px blocks, 2 waves, reg-capped
__global__ __launch_bounds__(128, 2) void conv_win(
    const unsigned short* __restrict__ Xt,
    const unsigned short* __restrict__ Wb,
    float* __restrict__ out) {
  __shared__ __align__(16) unsigned short lds[16384];   // 32 KB: 2 window buffers
  char* const ldsb = (char*)lds;

  const int tid  = threadIdx.x;
  const int lane = tid & 63;
  const int wm   = tid >> 6;             // 2 waves: M halves; wave tile 64oc x 112px
  const int l15 = lane & 15, lh = lane >> 4;

  // XCD-aware bijective remap: 1792 = 8 x 224; wg pairs share a pixel tile
  const int bid = blockIdx.x;
  const int wg  = (bid & 7) * 224 + (bid >> 3);
  const int pt  = wg >> 1;               // pixel-tile 0..895
  const int ocb = (wg & 1) * 128;
  const int n   = pt / 28;
  const int rt  = pt - n * 28;           // row-pair within image
  const int y0  = rt * 2;                // padded top row of window (4 rows)

  // ---- A source: per-lane VGPR loads, coalesced (16 lanes x 16B contiguous)
  const unsigned short* aBase = Wb + (size_t)lh * 2048 + (ocb + wm * 64 + l15) * 8;

  // ---- window staging sources (8 slots/thread; content layout [4][58 cols][64B])
  const unsigned short* srcW[8];
  #pragma unroll
  for (int r = 0; r < 8; ++r) {
    int xw = swz((r * 128 + tid) * 16);
    if (xw >= WINREAL) xw = WINREAL - 16;          // slack slots: dup (never read)
    int row = xw / WROWB;
    int rem = xw - row * WROWB;
    int col = rem >> 6;
    srcW[r] = Xt + ((long)((n * PH + y0 + row) * PW + col)) * IC + ((rem & 63) >> 1);
  }

  // ---- fragment linear offsets (window, stride-58 rows)
  int pixLin[7];
  #pragma unroll
  for (int j = 0; j < 7; ++j) {
    int local = j * 16 + l15;                // 0..111 within block
    int wy = local / 56, wx = local - wy * 56;
    pixLin[j] = (wy * 58 + wx) * 64 + lh * 16;
  }

  f32x4 acc[4][7];
  #pragma unroll
  for (int m = 0; m < 4; ++m)
    #pragma unroll
    for (int j = 0; j < 7; ++j)
      acc[m][j] = (f32x4){0.f, 0.f, 0.f, 0.f};

  auto stageWin = [&](int icb) {          // slice icb -> buf (icb&1); wave-uniform dest
    char* base = ldsb + (icb & 1) * WINB + (tid & ~63) * 16;
    #pragma unroll
    for (int r = 0; r < 8; ++r)
      gload16(srcW[r] + icb * 32, (unsigned short*)(base + r * 2048));
  };

  // ---- prologue
  stageWin(0);
  bf16x8 aReg[2][4];
  #pragma unroll
  for (int m = 0; m < 4; ++m)
    aReg[0][m] = *(const bf16x8*)(aBase + m * 128);        // A(q=0): tap0, icb0
  asm volatile("s_waitcnt vmcnt(0)" ::: "memory");
  __builtin_amdgcn_s_barrier();
  __builtin_amdgcn_sched_barrier(0);

  for (int icb = 0; icb < 4; ++icb) {
    const int winSel = (icb & 1) * WINB;

    #pragma unroll
    for (int tap = 0; tap < 9; ++tap) {
      // global tap parity: q = icb*9+tap ; 9 odd => q&1 == (icb+tap)&1
      const int rs = (icb + tap) & 1;          // read slot
      const int ps = rs ^ 1;                   // prefetch slot (q+1)

      // prefetch A for q+1 (never collides: ps != rs)
      if (tap < 8) {
        #pragma unroll
        for (int m = 0; m < 4; ++m)
          aReg[ps][m] = *(const bf16x8*)(aBase + (size_t)(tap + 1) * 32768
                                               + (size_t)icb * 8192 + m * 128);
      } else if (icb < 3) {
        #pragma unroll
        for (int m = 0; m < 4; ++m)
          aReg[ps][m] = *(const bf16x8*)(aBase + (size_t)(icb + 1) * 8192 + m * 128);
      }

      const int dy = tap / 3, dx = tap - dy * 3;   // compile-time (tap unrolled)
      const int toff = (dy * 58 + dx) * 64;

      bf16x8 bfv[7];
      #pragma unroll
      for (int j = 0; j < 7; ++j)
        bfv[j] = *(const bf16x8*)(ldsb + winSel + swz(pixLin[j] + toff));

      __builtin_amdgcn_s_setprio(1);
      #pragma unroll
      for (int j = 0; j < 7; ++j)
        #pragma unroll
        for (int m = 0; m < 4; ++m)
          acc[m][j] = __builtin_amdgcn_mfma_f32_16x16x32_bf16(aReg[rs][m], bfv[j],
                                                              acc[m][j], 0, 0, 0);
      __builtin_amdgcn_s_setprio(0);

      // FIFO-aware staging: issue after tap 4 so A-prefetch waits at taps<=5 do not
      // force-retire the staging burst (vmcnt retires oldest-first).
      if (tap == 4 && icb < 3) stageWin(icb + 1);
    }

    // window(icb+1) fully staged (both waves) before reading it; WAR on buf icb&1
    // certified for the stage at icb+2 by this same barrier.
    asm volatile("s_waitcnt vmcnt(0)" ::: "memory");
    __builtin_amdgcn_s_barrier();
    __builtin_amdgcn_sched_barrier(0);
  }

  // ---- epilogue: D row=(lane>>4)*4+reg (oc), col=lane&15 (pixel)
  #pragma unroll
  for (int j = 0; j < 7; ++j) {
    int pidx = rt * BNP + j * 16 + l15;           // pixel within image
    #pragma unroll
    for (int m = 0; m < 4; ++m) {
      int oc = ocb + wm * 64 + m * 16 + lh * 4;
      float* op = out + ((long)(n * OC + oc)) * NPIX + pidx;
      #pragma unroll
      for (int r = 0; r < 4; ++r)
        op[(long)r * NPIX] = acc[m][j][r];
    }
  }
}

// ---- fallback: naive direct conv fp32
__global__ __launch_bounds__(256) void conv_naive(const float* __restrict__ X,
                                                  const float* __restrict__ W,
                                                  float* __restrict__ out, int total) {
  int idx = blockIdx.x * 256 + threadIdx.x;
  if (idx >= total) return;
  int prow = idx % NPIX;
  int t    = idx / NPIX;
  int oc   = t % OC;
  int n    = t / OC;
  int oh = prow / WW, ow = prow % WW;
  float s = 0.f;
  for (int ic = 0; ic < IC; ++ic) {
    const float* xp = X + ((long)(n * IC + ic)) * NPIX;
    const float* wp = W + ((long)(oc * IC + ic)) * 9;
    #pragma unroll
    for (int kh = 0; kh < 3; ++kh) {
      int ih = oh + kh - 1;
      if (ih < 0 || ih >= HH) continue;
      #pragma unroll
      for (int kw = 0; kw < 3; ++kw) {
        int iw = ow + kw - 1;
        if (iw < 0 || iw >= WW) continue;
        s += xp[ih * WW + iw] * wp[kh * 3 + kw];
      }
    }
  }
  out[idx] = s;
}

extern "C" void kernel_launch(void* const* d_in, const int* in_sizes, int n_in,
                              void* d_out, int out_size, void* d_ws, size_t ws_size,
                              hipStream_t stream) {
  const float* X = (const float*)d_in[0];
  const float* W = (const float*)d_in[1];
  float* out = (float*)d_out;

  const size_t xt_elems = (size_t)NB * PS * IC;
  const size_t wb_elems = (size_t)9 * 16 * 256 * 8;   // 294,912
  const size_t need = (xt_elems + wb_elems) * sizeof(unsigned short);

  if (ws_size >= need) {
    unsigned short* Xt = (unsigned short*)d_ws;
    unsigned short* Wb = Xt + xt_elems;

    prep<<<PADBLK + BORDBLK + WBLK, 256, 0, stream>>>(X, W, Xt, Wb);
    conv_win<<<(GPIX / BNP) * (OC / 128), 128, 0, stream>>>(Xt, Wb, out);
  } else {
    int tot = NB * OC * NPIX;
    conv_naive<<<(tot + 255) / 256, 256, 0, stream>>>(X, W, out, tot);
  }
}